// Round 1
// 819.749 us; speedup vs baseline: 1.1467x; 1.1467x over previous
//
#include <hip/hip_runtime.h>
#include <hip/hip_bf16.h>
#include <stdint.h>

// B=16, N=4096, C=768, H=8, D=96
// Pipeline: cvt(x,wqkv,wproj) -> qkv gemm (256^2 8-phase bf16 mfma) -> q^T k + softmax -> attn@v -> proj gemm
typedef __bf16 bf16;
typedef __bf16 bf16x8 __attribute__((ext_vector_type(8)));
typedef __bf16 bf16x4 __attribute__((ext_vector_type(4)));
typedef float f32x4 __attribute__((ext_vector_type(4)));

__device__ __forceinline__ void gl_lds16(const bf16* g, bf16* l) {
  __builtin_amdgcn_global_load_lds(
      (const __attribute__((address_space(1))) void*)g,
      (__attribute__((address_space(3))) void*)l, 16, 0, 0);
}

__global__ void cvt_f32_bf16(const float* __restrict__ in, bf16* __restrict__ out, int n4) {
  int i = blockIdx.x * blockDim.x + threadIdx.x;
  if (i < n4) {
    float4 v = ((const float4*)in)[i];
    bf16x4 o;
    o[0] = (bf16)v.x; o[1] = (bf16)v.y; o[2] = (bf16)v.z; o[3] = (bf16)v.w;
    ((bf16x4*)out)[i] = o;
  }
}

// ---------------- 256x256 8-phase GEMM (C = A * B^T + bias) ----------------
// Tile 256x256, BK=64, 8 waves (2M x 4N), per-wave 128x64 output.
// LDS: 2 buf x (A 256x64 + B 256x64) bf16 = 128 KiB.
// Swizzle: LDS chunk (row, ci') holds global k-chunk ci = ci' ^ (row&7); 16B chunks.
//  -> ds_read_b128 of a 16-row fragment column: lanes 0-7 cover all 32 banks. Conflict-free.
//  -> global_load_lds dest stays linear (wave base + lane*16); SOURCE address carries the XOR.
// Half-regions (16 KB each, staged by one call = 2 gl_lds per wave):
//  A-lo = rows {0-63,128-191} (mi 0-3 for both wm), A-hi = complement
//  B-lo = rows {0-31,64-95,128-159,192-223} (ni 0-1 for all wn), B-hi = complement
// Phase schedule per K-tile t (quadrants lo-lo, lo-hi, hi-hi, hi-lo):
//  ph1: read A-lo+B-lo frags, stage B-lo(t+1)->buf^1 ; ph2: read B-hi, stage A-lo(t+2)->buf
//  ph3: read A-hi, stage B-hi(t+2)->buf ; ph4: no reads, stage A-hi(t+2)->buf, vmcnt(6)
// Each stage only overwrites a region whose reads retired a phase earlier (barrier-protected).
// vmcnt(6) = 3 half-tiles (2 loads each) in flight; vmcnt(0) for the last two tiles.

template<int OP, int HALF>  // OP 0=A,1=B ; HALF 0=lo,1=hi
__device__ __forceinline__ void stage_half(const bf16* __restrict__ G, long r0, int k0,
                                           int K, bf16* ldsOp, int w, int lane) {
#pragma unroll
  for (int j = 0; j < 2; ++j) {
    int rr8 = (w * 2 + j) * 8;
    int rb = (OP == 0) ? ((rr8 & 63) + ((rr8 >> 6) << 7) + HALF * 64)
                       : ((rr8 & 31) + ((rr8 >> 5) << 6) + HALF * 32);
    int row = rb + (lane >> 3);
    int ci = (lane & 7) ^ (row & 7);  // inverse-swizzled source chunk
    gl_lds16(G + (r0 + row) * (long)K + k0 + ci * 8, ldsOp + rb * 64);
  }
}

#define AF(buf_, mi_, ksel_) (*(const bf16x8*)&lds[buf_][0][aoff0 + (mi_) * 1024 + (ksel_)])
#define BF(buf_, ni_, ksel_) (*(const bf16x8*)&lds[buf_][1][boff0 + (ni_) * 1024 + (ksel_)])
#define MFMA16(a_, b_, c_) c_ = __builtin_amdgcn_mfma_f32_16x16x32_bf16(a_, b_, c_, 0, 0, 0)

#define TILE(t_, buf_) do {                                                         \
    bf16x8 af[4][2], bl[2][2], bh[2][2];                                            \
    /* phase 1: A-lo + B-lo reads, stage B-lo(t+1) */                               \
    _Pragma("unroll") for (int mi = 0; mi < 4; mi++) {                              \
      af[mi][0] = AF(buf_, mi, ks0); af[mi][1] = AF(buf_, mi, ks1); }               \
    _Pragma("unroll") for (int ni = 0; ni < 2; ni++) {                              \
      bl[ni][0] = BF(buf_, ni, ks0); bl[ni][1] = BF(buf_, ni, ks1); }               \
    if ((t_) + 1 < T) stage_half<1, 0>(B, n0, ((t_) + 1) * 64, K,                   \
                                       &lds[(buf_) ^ 1][1][0], w, lane);            \
    __builtin_amdgcn_s_barrier();                                                   \
    asm volatile("s_waitcnt lgkmcnt(0)" ::: "memory");                              \
    __builtin_amdgcn_s_setprio(1);                                                  \
    _Pragma("unroll") for (int mi = 0; mi < 4; mi++)                                \
      _Pragma("unroll") for (int ni = 0; ni < 2; ni++) {                            \
        MFMA16(af[mi][0], bl[ni][0], acc[mi][ni]);                                  \
        MFMA16(af[mi][1], bl[ni][1], acc[mi][ni]); }                                \
    __builtin_amdgcn_s_setprio(0);                                                  \
    __builtin_amdgcn_s_barrier();                                                   \
    /* phase 2: B-hi reads, stage A-lo(t+2) */                                      \
    _Pragma("unroll") for (int ni = 0; ni < 2; ni++) {                              \
      bh[ni][0] = BF(buf_, 2 + ni, ks0); bh[ni][1] = BF(buf_, 2 + ni, ks1); }       \
    if ((t_) + 2 < T) stage_half<0, 0>(A, m0, ((t_) + 2) * 64, K,                   \
                                       &lds[buf_][0][0], w, lane);                  \
    __builtin_amdgcn_s_barrier();                                                   \
    asm volatile("s_waitcnt lgkmcnt(0)" ::: "memory");                              \
    __builtin_amdgcn_s_setprio(1);                                                  \
    _Pragma("unroll") for (int mi = 0; mi < 4; mi++)                                \
      _Pragma("unroll") for (int ni = 0; ni < 2; ni++) {                            \
        MFMA16(af[mi][0], bh[ni][0], acc[mi][2 + ni]);                              \
        MFMA16(af[mi][1], bh[ni][1], acc[mi][2 + ni]); }                            \
    __builtin_amdgcn_s_setprio(0);                                                  \
    __builtin_amdgcn_s_barrier();                                                   \
    /* phase 3: A-hi reads, stage B-hi(t+2) */                                      \
    _Pragma("unroll") for (int mi = 0; mi < 4; mi++) {                              \
      af[mi][0] = AF(buf_, 4 + mi, ks0); af[mi][1] = AF(buf_, 4 + mi, ks1); }       \
    if ((t_) + 2 < T) stage_half<1, 1>(B, n0, ((t_) + 2) * 64, K,                   \
                                       &lds[buf_][1][0], w, lane);                  \
    __builtin_amdgcn_s_barrier();                                                   \
    asm volatile("s_waitcnt lgkmcnt(0)" ::: "memory");                              \
    __builtin_amdgcn_s_setprio(1);                                                  \
    _Pragma("unroll") for (int mi = 0; mi < 4; mi++)                                \
      _Pragma("unroll") for (int ni = 0; ni < 2; ni++) {                            \
        MFMA16(af[mi][0], bh[ni][0], acc[4 + mi][2 + ni]);                          \
        MFMA16(af[mi][1], bh[ni][1], acc[4 + mi][2 + ni]); }                        \
    __builtin_amdgcn_s_setprio(0);                                                  \
    __builtin_amdgcn_s_barrier();                                                   \
    /* phase 4: no reads, stage A-hi(t+2), counted vmcnt */                         \
    if ((t_) + 2 < T) stage_half<0, 1>(A, m0, ((t_) + 2) * 64, K,                   \
                                       &lds[buf_][0][0], w, lane);                  \
    if ((t_) >= T - 2) { asm volatile("s_waitcnt vmcnt(0)" ::: "memory"); }         \
    else               { asm volatile("s_waitcnt vmcnt(6)" ::: "memory"); }         \
    __builtin_amdgcn_s_barrier();                                                   \
    __builtin_amdgcn_s_setprio(1);                                                  \
    _Pragma("unroll") for (int mi = 0; mi < 4; mi++)                                \
      _Pragma("unroll") for (int ni = 0; ni < 2; ni++) {                            \
        MFMA16(af[mi][0], bl[ni][0], acc[4 + mi][ni]);                              \
        MFMA16(af[mi][1], bl[ni][1], acc[4 + mi][ni]); }                            \
    __builtin_amdgcn_s_setprio(0);                                                  \
    __builtin_amdgcn_s_barrier();                                                   \
  } while (0)

// EPI=0: bf16 out + bias, scale cols<768 by N^-0.5 (qkv). EPI=1: fp32 out + bias (proj).
template<int EPI>
__global__ __launch_bounds__(512, 2) void gemm256(
    const bf16* __restrict__ A, const bf16* __restrict__ B,
    const float* __restrict__ bias, void* __restrict__ Cout,
    int N, int K, int nbn, int nwg)
{
  __shared__ __align__(16) bf16 lds[2][2][256 * 64];
  int bid = blockIdx.x;
  int swz = (bid & 7) * (nwg >> 3) + (bid >> 3);  // XCD-contiguous chunks (nwg%8==0)
  long m0 = (long)(swz / nbn) * 256;
  int n0i = (swz % nbn) * 256;
  long n0 = n0i;
  int t = threadIdx.x;
  int w = t >> 6, lane = t & 63;
  int wm = w >> 2, wn = w & 3;
  int l16 = lane & 15, quad = lane >> 4;
  int s7 = l16 & 7;
  int aoff0 = (wm * 128 + l16) * 64;
  int boff0 = (wn * 64 + l16) * 64;
  int ks0 = (quad ^ s7) * 8;        // swizzled chunk offset, k-slice 0
  int ks1 = ((4 + quad) ^ s7) * 8;  // k-slice 1
  const int T = K >> 6;             // 12 K-tiles

  f32x4 acc[8][4] = {};

  // prologue: tile0 {A-lo,B-hi,A-hi,B-lo} then tile1 {A-lo,B-hi,A-hi} = 14 loads
  stage_half<0, 0>(A, m0, 0, K, &lds[0][0][0], w, lane);
  stage_half<1, 1>(B, n0, 0, K, &lds[0][1][0], w, lane);
  stage_half<0, 1>(A, m0, 0, K, &lds[0][0][0], w, lane);
  stage_half<1, 0>(B, n0, 0, K, &lds[0][1][0], w, lane);
  stage_half<0, 0>(A, m0, 64, K, &lds[1][0][0], w, lane);
  stage_half<1, 1>(B, n0, 64, K, &lds[1][1][0], w, lane);
  stage_half<0, 1>(A, m0, 64, K, &lds[1][0][0], w, lane);
  asm volatile("s_waitcnt vmcnt(6)" ::: "memory");  // tile 0 fully landed
  __builtin_amdgcn_s_barrier();

  for (int tt = 0; tt < T; tt += 2) {
    TILE(tt, 0);
    TILE(tt + 1, 1);
  }

  long crow0 = m0 + wm * 128 + quad * 4;
  int ccol0 = n0i + wn * 64 + l16;
#pragma unroll
  for (int mi = 0; mi < 8; mi++) {
#pragma unroll
    for (int ni = 0; ni < 4; ni++) {
      int col = ccol0 + ni * 16;
      float bv = bias[col];
#pragma unroll
      for (int r = 0; r < 4; r++) {
        float v = acc[mi][ni][r] + bv;
        long row = crow0 + mi * 16 + r;
        if (EPI == 0) {
          if (col < 768) v *= 0.015625f;  // q * N^-0.5
          ((bf16*)Cout)[row * (long)N + col] = (bf16)v;
        } else {
          ((float*)Cout)[row * (long)N + col] = v;
        }
      }
    }
  }
}

// attn partials: part[bh][kb][d][e] = sum_{n in half kb} q[n,d] * k[n,e]
__global__ __launch_bounds__(256) void attn_qk(const bf16* __restrict__ qkv, float* __restrict__ part)
{
  __shared__ __align__(16) bf16 sQ[96 * 72];
  __shared__ __align__(16) bf16 sK[96 * 72];
  int bh = blockIdx.x >> 1, kb = blockIdx.x & 1;
  int b = bh >> 3, h = bh & 7;
  int t = threadIdx.x;
  int wave = t >> 6, lane = t & 63;
  int wm = wave >> 1, wn = wave & 1;
  int l16 = lane & 15, quad = lane >> 4;
  f32x4 acc[3][3] = {};
  const bf16* Qb = qkv + (long)b * 4096 * 2304 + h * 96;
  const bf16* Kb = Qb + 768;

  for (int it = 0; it < 32; it++) {
    int tok0 = kb * 2048 + it * 64;
    __syncthreads();
#pragma unroll
    for (int i = 0; i < 3; i++) {
      int id = i * 256 + t;
      int tl = id / 12, cc = id % 12;
      uint4 q4 = *(const uint4*)(Qb + (long)(tok0 + tl) * 2304 + cc * 8);
      uint4 k4 = *(const uint4*)(Kb + (long)(tok0 + tl) * 2304 + cc * 8);
      const bf16* qe = (const bf16*)&q4;
      const bf16* ke = (const bf16*)&k4;
#pragma unroll
      for (int j = 0; j < 8; j++) {
        sQ[(cc * 8 + j) * 72 + tl] = qe[j];
        sK[(cc * 8 + j) * 72 + tl] = ke[j];
      }
    }
    __syncthreads();
#pragma unroll
    for (int ks = 0; ks < 2; ks++) {
      bf16x8 af[3], bfr[3];
#pragma unroll
      for (int mi = 0; mi < 3; mi++)
        af[mi] = *(const bf16x8*)&sQ[(wm * 48 + mi * 16 + l16) * 72 + ks * 32 + quad * 8];
#pragma unroll
      for (int ni = 0; ni < 3; ni++)
        bfr[ni] = *(const bf16x8*)&sK[(wn * 48 + ni * 16 + l16) * 72 + ks * 32 + quad * 8];
#pragma unroll
      for (int mi = 0; mi < 3; mi++)
#pragma unroll
        for (int ni = 0; ni < 3; ni++)
          acc[mi][ni] = __builtin_amdgcn_mfma_f32_16x16x32_bf16(af[mi], bfr[ni], acc[mi][ni], 0, 0, 0);
    }
  }
  float* pout = part + (long)(bh * 2 + kb) * 9216;
#pragma unroll
  for (int mi = 0; mi < 3; mi++)
#pragma unroll
    for (int ni = 0; ni < 3; ni++) {
      int row = wm * 48 + mi * 16 + quad * 4;
      int col = wn * 48 + ni * 16 + l16;
#pragma unroll
      for (int r = 0; r < 4; r++)
        pout[(row + r) * 96 + col] = acc[mi][ni][r];
    }
}

// sum 2 partials, row softmax over e, cast bf16
__global__ __launch_bounds__(256) void softmax_attn(const float* __restrict__ part, bf16* __restrict__ attn)
{
  __shared__ float s[96 * 97];
  int bh = blockIdx.x;
  int t = threadIdx.x;
  const float* p0 = part + (long)bh * 2 * 9216;
  const float* p1 = p0 + 9216;
  for (int e = t; e < 9216; e += 256) {
    int r = e / 96, c = e % 96;
    s[r * 97 + c] = p0[e] + p1[e];
  }
  __syncthreads();
  if (t < 96) {
    float m = -1e30f;
    for (int i = 0; i < 96; i++) m = fmaxf(m, s[t * 97 + i]);
    float sum = 0.f;
    for (int i = 0; i < 96; i++) {
      float ev = __expf(s[t * 97 + i] - m);
      s[t * 97 + i] = ev;
      sum += ev;
    }
    float inv = 1.f / sum;
    bf16* ao = attn + (long)bh * 9216 + t * 96;
    for (int i = 0; i < 96; i++) ao[i] = (bf16)(s[t * 97 + i] * inv);
  }
}

// out2[tok, h*96+d] = sum_e v[tok,e] * attn[d,e]
__global__ __launch_bounds__(256) void attn_v(
    const bf16* __restrict__ qkv, const bf16* __restrict__ attn, bf16* __restrict__ out2)
{
  __shared__ __align__(16) bf16 sV[128 * 96];
  __shared__ __align__(16) bf16 sAt[96 * 96];
  int bh = blockIdx.x >> 5, tb = blockIdx.x & 31;
  int b = bh >> 3, h = bh & 7;
  int tok0 = tb * 128;
  int t = threadIdx.x;
  int wave = t >> 6, lane = t & 63;
  int wm = wave >> 1, wn = wave & 1;
  int l16 = lane & 15, quad = lane >> 4;
  f32x4 acc[4][3] = {};
  const bf16* Vb = qkv + (long)b * 4096 * 2304 + 1536 + h * 96;

#pragma unroll
  for (int j = 0; j < 6; j++) {
    int c = wave * 6 + j;
    int g = c * 64 + lane;
    int tok = g / 12, cc = g % 12;
    gl_lds16(Vb + (long)(tok0 + tok) * 2304 + cc * 8, &sV[c * 512]);
  }
  for (int c = wave; c < 18; c += 4) {
    int g = c * 64 + lane;
    int d = g / 12, cc = g % 12;
    gl_lds16(attn + (long)bh * 9216 + d * 96 + cc * 8, &sAt[c * 512]);
  }
  __syncthreads();
#pragma unroll
  for (int ks = 0; ks < 3; ks++) {
    bf16x8 af[4], bfr[3];
#pragma unroll
    for (int mi = 0; mi < 4; mi++)
      af[mi] = *(const bf16x8*)&sV[(wm * 64 + mi * 16 + l16) * 96 + ks * 32 + quad * 8];
#pragma unroll
    for (int ni = 0; ni < 3; ni++)
      bfr[ni] = *(const bf16x8*)&sAt[(wn * 48 + ni * 16 + l16) * 96 + ks * 32 + quad * 8];
#pragma unroll
    for (int mi = 0; mi < 4; mi++)
#pragma unroll
      for (int ni = 0; ni < 3; ni++)
        acc[mi][ni] = __builtin_amdgcn_mfma_f32_16x16x32_bf16(af[mi], bfr[ni], acc[mi][ni], 0, 0, 0);
  }
  bf16* ob = out2 + (long)(b * 4096 + tok0) * 768 + h * 96;
#pragma unroll
  for (int mi = 0; mi < 4; mi++)
#pragma unroll
    for (int ni = 0; ni < 3; ni++) {
      int row = wm * 64 + mi * 16 + quad * 4;
      int col = wn * 48 + ni * 16 + l16;
#pragma unroll
      for (int r = 0; r < 4; r++)
        ob[(long)(row + r) * 768 + col] = (bf16)acc[mi][ni][r];
    }
}

extern "C" void kernel_launch(void* const* d_in, const int* in_sizes, int n_in,
                              void* d_out, int out_size, void* d_ws, size_t ws_size,
                              hipStream_t stream) {
  const float* x      = (const float*)d_in[0];
  const float* w_qkv  = (const float*)d_in[1];
  const float* b_qkv  = (const float*)d_in[2];
  const float* w_proj = (const float*)d_in[3];
  const float* b_proj = (const float*)d_in[4];

  char* ws = (char*)d_ws;
  bf16*  Xb     = (bf16*)ws;                      // 100,663,296 B
  bf16*  Wqkvb  = (bf16*)(ws + 100663296);        //   3,538,944 B
  bf16*  Wprojb = (bf16*)(ws + 104202240);        //   1,179,648 B
  bf16*  qkvb   = (bf16*)(ws + 105381888);        // 301,989,888 B
  float* part   = (float*)(ws + 407371776);       //   9,437,184 B
  bf16*  attnb  = (bf16*)(ws + 416808960);        //   2,359,296 B
  bf16*  out2   = (bf16*)ws;                      // reuse X region (dead after qkv gemm)

  cvt_f32_bf16<<<(12582912 + 255) / 256, 256, 0, stream>>>(x, Xb, 12582912);
  cvt_f32_bf16<<<(442368 + 255) / 256, 256, 0, stream>>>(w_qkv, Wqkvb, 442368);
  cvt_f32_bf16<<<(147456 + 255) / 256, 256, 0, stream>>>(w_proj, Wprojb, 147456);

  // qkv = x @ w_qkv^T + b (q scaled), bf16 out [65536, 2304]; 256x9=2304 blocks
  gemm256<0><<<2304, 512, 0, stream>>>(Xb, Wqkvb, b_qkv, qkvb, 2304, 768, 9, 2304);
  // attn partials per (b,h), split-K=2 over tokens
  attn_qk<<<256, 256, 0, stream>>>(qkvb, part);
  softmax_attn<<<128, 256, 0, stream>>>(part, attnb);
  // out2 = (attn @ v^T)^T merged heads -> [65536, 768] bf16
  attn_v<<<4096, 256, 0, stream>>>(qkvb, attnb, out2);
  // final: out2 @ w_proj^T + b -> fp32 d_out; 256x3=768 blocks
  gemm256<1><<<768, 512, 0, stream>>>(out2, Wprojb, b_proj, d_out, 768, 768, 3, 768);
}

// Round 3
// 786.782 us; speedup vs baseline: 1.1948x; 1.0419x over previous
//
#include <hip/hip_runtime.h>
#include <hip/hip_bf16.h>
#include <stdint.h>

// B=16, N=4096, C=768, H=8, D=96
// Pipeline: cvt -> qkv gemm (256^2 8-phase, Q/K written TRANSPOSED [c][tok], V normal)
//           -> attn_qk (clean split-K GEMM over tokens) -> softmax -> attn@v -> proj gemm
typedef __bf16 bf16;
typedef __bf16 bf16x8 __attribute__((ext_vector_type(8)));
typedef __bf16 bf16x4 __attribute__((ext_vector_type(4)));
typedef float f32x4 __attribute__((ext_vector_type(4)));

__device__ __forceinline__ void gl_lds16(const bf16* g, bf16* l) {
  __builtin_amdgcn_global_load_lds(
      (const __attribute__((address_space(1))) void*)g,
      (__attribute__((address_space(3))) void*)l, 16, 0, 0);
}

__global__ void cvt_f32_bf16(const float* __restrict__ in, bf16* __restrict__ out, int n4) {
  int i = blockIdx.x * blockDim.x + threadIdx.x;
  if (i < n4) {
    float4 v = ((const float4*)in)[i];
    bf16x4 o;
    o[0] = (bf16)v.x; o[1] = (bf16)v.y; o[2] = (bf16)v.z; o[3] = (bf16)v.w;
    ((bf16x4*)out)[i] = o;
  }
}

// ---------------- 256x256 8-phase GEMM (C = A * B^T + bias) ----------------
// Main loop identical to round-1 verified version (swizzled LDS, counted vmcnt, setprio).
// EPI=0 epilogue: n0i<1536 -> transposed q/k write to qkT[(b*1536+c)*4096+tok] (bf16x4 packs
//                 4 consecutive tokens; q cols scaled); n0i>=1536 -> V write to Vb[tok][768].
// EPI=1 epilogue: fp32 out + bias (proj).

template<int OP, int HALF>  // OP 0=A,1=B ; HALF 0=lo,1=hi
__device__ __forceinline__ void stage_half(const bf16* __restrict__ G, long r0, int k0,
                                           int K, bf16* ldsOp, int w, int lane) {
#pragma unroll
  for (int j = 0; j < 2; ++j) {
    int rr8 = (w * 2 + j) * 8;
    int rb = (OP == 0) ? ((rr8 & 63) + ((rr8 >> 6) << 7) + HALF * 64)
                       : ((rr8 & 31) + ((rr8 >> 5) << 6) + HALF * 32);
    int row = rb + (lane >> 3);
    int ci = (lane & 7) ^ (row & 7);  // inverse-swizzled source chunk
    gl_lds16(G + (r0 + row) * (long)K + k0 + ci * 8, ldsOp + rb * 64);
  }
}

#define AF(buf_, mi_, ksel_) (*(const bf16x8*)&lds[buf_][0][aoff0 + (mi_) * 1024 + (ksel_)])
#define BF(buf_, ni_, ksel_) (*(const bf16x8*)&lds[buf_][1][boff0 + (ni_) * 1024 + (ksel_)])
#define MFMA16(a_, b_, c_) c_ = __builtin_amdgcn_mfma_f32_16x16x32_bf16(a_, b_, c_, 0, 0, 0)

#define TILE(t_, buf_) do {                                                         \
    bf16x8 af[4][2], bl[2][2], bh[2][2];                                            \
    /* phase 1: A-lo + B-lo reads, stage B-lo(t+1) */                               \
    _Pragma("unroll") for (int mi = 0; mi < 4; mi++) {                              \
      af[mi][0] = AF(buf_, mi, ks0); af[mi][1] = AF(buf_, mi, ks1); }               \
    _Pragma("unroll") for (int ni = 0; ni < 2; ni++) {                              \
      bl[ni][0] = BF(buf_, ni, ks0); bl[ni][1] = BF(buf_, ni, ks1); }               \
    if ((t_) + 1 < T) stage_half<1, 0>(B, n0, ((t_) + 1) * 64, K,                   \
                                       &lds[(buf_) ^ 1][1][0], w, lane);            \
    __builtin_amdgcn_s_barrier();                                                   \
    asm volatile("s_waitcnt lgkmcnt(0)" ::: "memory");                              \
    __builtin_amdgcn_s_setprio(1);                                                  \
    _Pragma("unroll") for (int mi = 0; mi < 4; mi++)                                \
      _Pragma("unroll") for (int ni = 0; ni < 2; ni++) {                            \
        MFMA16(af[mi][0], bl[ni][0], acc[mi][ni]);                                  \
        MFMA16(af[mi][1], bl[ni][1], acc[mi][ni]); }                                \
    __builtin_amdgcn_s_setprio(0);                                                  \
    __builtin_amdgcn_s_barrier();                                                   \
    /* phase 2: B-hi reads, stage A-lo(t+2) */                                      \
    _Pragma("unroll") for (int ni = 0; ni < 2; ni++) {                              \
      bh[ni][0] = BF(buf_, 2 + ni, ks0); bh[ni][1] = BF(buf_, 2 + ni, ks1); }       \
    if ((t_) + 2 < T) stage_half<0, 0>(A, m0, ((t_) + 2) * 64, K,                   \
                                       &lds[buf_][0][0], w, lane);                  \
    __builtin_amdgcn_s_barrier();                                                   \
    asm volatile("s_waitcnt lgkmcnt(0)" ::: "memory");                              \
    __builtin_amdgcn_s_setprio(1);                                                  \
    _Pragma("unroll") for (int mi = 0; mi < 4; mi++)                                \
      _Pragma("unroll") for (int ni = 0; ni < 2; ni++) {                            \
        MFMA16(af[mi][0], bh[ni][0], acc[mi][2 + ni]);                              \
        MFMA16(af[mi][1], bh[ni][1], acc[mi][2 + ni]); }                            \
    __builtin_amdgcn_s_setprio(0);                                                  \
    __builtin_amdgcn_s_barrier();                                                   \
    /* phase 3: A-hi reads, stage B-hi(t+2) */                                      \
    _Pragma("unroll") for (int mi = 0; mi < 4; mi++) {                              \
      af[mi][0] = AF(buf_, 4 + mi, ks0); af[mi][1] = AF(buf_, 4 + mi, ks1); }       \
    if ((t_) + 2 < T) stage_half<1, 1>(B, n0, ((t_) + 2) * 64, K,                   \
                                       &lds[buf_][1][0], w, lane);                  \
    __builtin_amdgcn_s_barrier();                                                   \
    asm volatile("s_waitcnt lgkmcnt(0)" ::: "memory");                              \
    __builtin_amdgcn_s_setprio(1);                                                  \
    _Pragma("unroll") for (int mi = 0; mi < 4; mi++)                                \
      _Pragma("unroll") for (int ni = 0; ni < 2; ni++) {                            \
        MFMA16(af[mi][0], bh[ni][0], acc[4 + mi][2 + ni]);                          \
        MFMA16(af[mi][1], bh[ni][1], acc[4 + mi][2 + ni]); }                        \
    __builtin_amdgcn_s_setprio(0);                                                  \
    __builtin_amdgcn_s_barrier();                                                   \
    /* phase 4: no reads, stage A-hi(t+2), counted vmcnt */                         \
    if ((t_) + 2 < T) stage_half<0, 1>(A, m0, ((t_) + 2) * 64, K,                   \
                                       &lds[buf_][0][0], w, lane);                  \
    if ((t_) >= T - 2) { asm volatile("s_waitcnt vmcnt(0)" ::: "memory"); }         \
    else               { asm volatile("s_waitcnt vmcnt(6)" ::: "memory"); }         \
    __builtin_amdgcn_s_barrier();                                                   \
    __builtin_amdgcn_s_setprio(1);                                                  \
    _Pragma("unroll") for (int mi = 0; mi < 4; mi++)                                \
      _Pragma("unroll") for (int ni = 0; ni < 2; ni++) {                            \
        MFMA16(af[mi][0], bl[ni][0], acc[4 + mi][ni]);                              \
        MFMA16(af[mi][1], bl[ni][1], acc[4 + mi][ni]); }                            \
    __builtin_amdgcn_s_setprio(0);                                                  \
    __builtin_amdgcn_s_barrier();                                                   \
  } while (0)

template<int EPI>
__global__ __launch_bounds__(512, 2) void gemm256(
    const bf16* __restrict__ A, const bf16* __restrict__ B,
    const float* __restrict__ bias, void* __restrict__ Cout, void* __restrict__ Cout2,
    int N, int K, int nbn, int nwg)
{
  __shared__ __align__(16) bf16 lds[2][2][256 * 64];
  int bid = blockIdx.x;
  int swz = (bid & 7) * (nwg >> 3) + (bid >> 3);  // XCD-contiguous chunks (nwg%8==0)
  long m0 = (long)(swz / nbn) * 256;
  int n0i = (swz % nbn) * 256;
  long n0 = n0i;
  int t = threadIdx.x;
  int w = t >> 6, lane = t & 63;
  int wm = w >> 2, wn = w & 3;
  int l16 = lane & 15, quad = lane >> 4;
  int s7 = l16 & 7;
  int aoff0 = (wm * 128 + l16) * 64;
  int boff0 = (wn * 64 + l16) * 64;
  int ks0 = (quad ^ s7) * 8;        // swizzled chunk offset, k-slice 0
  int ks1 = ((4 + quad) ^ s7) * 8;  // k-slice 1
  const int T = K >> 6;             // 12 K-tiles

  f32x4 acc[8][4] = {};

  // prologue: tile0 {A-lo,B-hi,A-hi,B-lo} then tile1 {A-lo,B-hi,A-hi} = 14 loads
  stage_half<0, 0>(A, m0, 0, K, &lds[0][0][0], w, lane);
  stage_half<1, 1>(B, n0, 0, K, &lds[0][1][0], w, lane);
  stage_half<0, 1>(A, m0, 0, K, &lds[0][0][0], w, lane);
  stage_half<1, 0>(B, n0, 0, K, &lds[0][1][0], w, lane);
  stage_half<0, 0>(A, m0, 64, K, &lds[1][0][0], w, lane);
  stage_half<1, 1>(B, n0, 64, K, &lds[1][1][0], w, lane);
  stage_half<0, 1>(A, m0, 64, K, &lds[1][0][0], w, lane);
  asm volatile("s_waitcnt vmcnt(6)" ::: "memory");  // tile 0 fully landed
  __builtin_amdgcn_s_barrier();

  for (int tt = 0; tt < T; tt += 2) {
    TILE(tt, 0);
    TILE(tt + 1, 1);
  }

  long crow0 = m0 + wm * 128 + quad * 4;
  int ccol0 = n0i + wn * 64 + l16;
  if (EPI == 0) {
    if (n0i < 1536) {
      // q/k -> transposed store qkT[(b*1536 + col)*4096 + tok], 4 toks packed per store
      long bidx = m0 >> 12;
      long tokb = (m0 & 4095) + wm * 128 + quad * 4;
      bf16* qkT = (bf16*)Cout;
#pragma unroll
      for (int ni = 0; ni < 4; ni++) {
        int col = ccol0 + ni * 16;
        float bv = bias[col];
        float sc = (col < 768) ? 0.015625f : 1.0f;  // q * N^-0.5
#pragma unroll
        for (int mi = 0; mi < 8; mi++) {
          bf16x4 pk;
#pragma unroll
          for (int r = 0; r < 4; r++) pk[r] = (bf16)((acc[mi][ni][r] + bv) * sc);
          *(bf16x4*)&qkT[(bidx * 1536 + col) * 4096 + tokb + mi * 16] = pk;
        }
      }
    } else {
      // v -> Vb[tok][768]
      bf16* Vb = (bf16*)Cout2;
#pragma unroll
      for (int mi = 0; mi < 8; mi++) {
#pragma unroll
        for (int ni = 0; ni < 4; ni++) {
          int col = ccol0 + ni * 16;
          float bv = bias[col];
          int colv = col - 1536;
#pragma unroll
          for (int r = 0; r < 4; r++) {
            long row = crow0 + mi * 16 + r;
            Vb[row * 768 + colv] = (bf16)(acc[mi][ni][r] + bv);
          }
        }
      }
    }
  } else {
#pragma unroll
    for (int mi = 0; mi < 8; mi++) {
#pragma unroll
      for (int ni = 0; ni < 4; ni++) {
        int col = ccol0 + ni * 16;
        float bv = bias[col];
#pragma unroll
        for (int r = 0; r < 4; r++) {
          long row = crow0 + mi * 16 + r;
          ((float*)Cout)[row * (long)N + col] = acc[mi][ni][r] + bv;
        }
      }
    }
  }
}

// attn partials: part[bh][s][d][e] = sum_{n in split s} qT[d,n] * kT[e,n]
// qkT layout: [b][c=0..1535][n=4096], q rows c=h*96+d, k rows c=768+h*96+e.
// Split-K=8 (512 tokens each) -> 1024 blocks, 4 waves (2x2 of 48x48), 48 KB LDS.
__global__ __launch_bounds__(256) void attn_qk(const bf16* __restrict__ qkT, float* __restrict__ part)
{
  __shared__ __align__(16) bf16 sQ[2][96 * 64];
  __shared__ __align__(16) bf16 sK[2][96 * 64];
  int s = blockIdx.x & 7, bh = blockIdx.x >> 3;
  int b = bh >> 3, h = bh & 7;
  int t = threadIdx.x;
  int w = t >> 6, lane = t & 63;
  int wm = w >> 1, wn = w & 1;
  int l16 = lane & 15, quad = lane >> 4;
  int s7 = l16 & 7;
  int ks0 = (quad ^ s7) * 8, ks1 = ((4 + quad) ^ s7) * 8;
  int wb = t & ~63;
  f32x4 acc[3][3] = {};
  const bf16* Arow = qkT + ((long)b * 1536 + h * 96) * 4096 + s * 512;
  const bf16* Brow = Arow + (long)768 * 4096;

  auto stage = [&](int buf, int k0) {
#pragma unroll
    for (int j = 0; j < 3; j++) {
      int g = j * 256 + t;
      int row = g >> 3;
      int ci = (g & 7) ^ (row & 7);  // inverse-swizzled source chunk
      int db = (j * 256 + wb) * 8;
      gl_lds16(Arow + (long)row * 4096 + k0 + ci * 8, &sQ[buf][db]);
      gl_lds16(Brow + (long)row * 4096 + k0 + ci * 8, &sK[buf][db]);
    }
  };

  stage(0, 0);
  for (int it = 0; it < 8; it++) {
    if (it < 7) {
      stage((it + 1) & 1, (it + 1) * 64);
      asm volatile("s_waitcnt vmcnt(6)" ::: "memory");
    } else {
      asm volatile("s_waitcnt vmcnt(0)" ::: "memory");
    }
    __builtin_amdgcn_s_barrier();
    int buf = it & 1;
#pragma unroll
    for (int ks = 0; ks < 2; ks++) {
      int ksel = ks ? ks1 : ks0;
      bf16x8 af[3], bfr[3];
#pragma unroll
      for (int mi = 0; mi < 3; mi++)
        af[mi] = *(const bf16x8*)&sQ[buf][(wm * 48 + mi * 16 + l16) * 64 + ksel];
#pragma unroll
      for (int ni = 0; ni < 3; ni++)
        bfr[ni] = *(const bf16x8*)&sK[buf][(wn * 48 + ni * 16 + l16) * 64 + ksel];
#pragma unroll
      for (int mi = 0; mi < 3; mi++)
#pragma unroll
        for (int ni = 0; ni < 3; ni++)
          acc[mi][ni] = __builtin_amdgcn_mfma_f32_16x16x32_bf16(af[mi], bfr[ni], acc[mi][ni], 0, 0, 0);
    }
    __builtin_amdgcn_s_barrier();
  }
  float* pout = part + ((long)bh * 8 + s) * 9216;
#pragma unroll
  for (int mi = 0; mi < 3; mi++)
#pragma unroll
    for (int ni = 0; ni < 3; ni++) {
      int row = wm * 48 + mi * 16 + quad * 4;
      int col = wn * 48 + ni * 16 + l16;
#pragma unroll
      for (int r = 0; r < 4; r++)
        pout[(row + r) * 96 + col] = acc[mi][ni][r];
    }
}

// sum 8 partials, row softmax over e, cast bf16
__global__ __launch_bounds__(256) void softmax_attn(const float* __restrict__ part, bf16* __restrict__ attn)
{
  __shared__ float s[96 * 97];
  int bh = blockIdx.x;
  int t = threadIdx.x;
  const float* p0 = part + (long)bh * 8 * 9216;
  for (int e = t; e < 9216; e += 256) {
    int r = e / 96, c = e % 96;
    float v = 0.f;
#pragma unroll
    for (int s2 = 0; s2 < 8; s2++) v += p0[s2 * 9216 + e];
    s[r * 97 + c] = v;
  }
  __syncthreads();
  if (t < 96) {
    float m = -1e30f;
    for (int i = 0; i < 96; i++) m = fmaxf(m, s[t * 97 + i]);
    float sum = 0.f;
    for (int i = 0; i < 96; i++) {
      float ev = __expf(s[t * 97 + i] - m);
      s[t * 97 + i] = ev;
      sum += ev;
    }
    float inv = 1.f / sum;
    bf16* ao = attn + (long)bh * 9216 + t * 96;
    for (int i = 0; i < 96; i++) ao[i] = (bf16)(s[t * 97 + i] * inv);
  }
}

// out2[tok, h*96+d] = sum_e v[tok,e] * attn[d,e] ; V layout [b*4096+tok][768]
__global__ __launch_bounds__(256) void attn_v(
    const bf16* __restrict__ Vb, const bf16* __restrict__ attn, bf16* __restrict__ out2)
{
  __shared__ __align__(16) bf16 sV[128 * 96];
  __shared__ __align__(16) bf16 sAt[96 * 96];
  int bh = blockIdx.x >> 5, tb = blockIdx.x & 31;
  int b = bh >> 3, h = bh & 7;
  int tok0 = tb * 128;
  int t = threadIdx.x;
  int wave = t >> 6, lane = t & 63;
  int wm = wave >> 1, wn = wave & 1;
  int l16 = lane & 15, quad = lane >> 4;
  f32x4 acc[4][3] = {};
  const bf16* Vbase = Vb + ((long)b * 4096 + tok0) * 768 + h * 96;

#pragma unroll
  for (int j = 0; j < 6; j++) {
    int c = wave * 6 + j;
    int g = c * 64 + lane;
    int tok = g / 12, cc = g % 12;
    gl_lds16(Vbase + (long)tok * 768 + cc * 8, &sV[c * 512]);
  }
  for (int c = wave; c < 18; c += 4) {
    int g = c * 64 + lane;
    int d = g / 12, cc = g % 12;
    gl_lds16(attn + (long)bh * 9216 + d * 96 + cc * 8, &sAt[c * 512]);
  }
  __syncthreads();
#pragma unroll
  for (int ks = 0; ks < 3; ks++) {
    bf16x8 af[4], bfr[3];
#pragma unroll
    for (int mi = 0; mi < 4; mi++)
      af[mi] = *(const bf16x8*)&sV[(wm * 64 + mi * 16 + l16) * 96 + ks * 32 + quad * 8];
#pragma unroll
    for (int ni = 0; ni < 3; ni++)
      bfr[ni] = *(const bf16x8*)&sAt[(wn * 48 + ni * 16 + l16) * 96 + ks * 32 + quad * 8];
#pragma unroll
    for (int mi = 0; mi < 4; mi++)
#pragma unroll
      for (int ni = 0; ni < 3; ni++)
        acc[mi][ni] = __builtin_amdgcn_mfma_f32_16x16x32_bf16(af[mi], bfr[ni], acc[mi][ni], 0, 0, 0);
  }
  bf16* ob = out2 + (long)(b * 4096 + tok0) * 768 + h * 96;
#pragma unroll
  for (int mi = 0; mi < 4; mi++)
#pragma unroll
    for (int ni = 0; ni < 3; ni++) {
      int row = wm * 64 + mi * 16 + quad * 4;
      int col = wn * 48 + ni * 16 + l16;
#pragma unroll
      for (int r = 0; r < 4; r++)
        ob[(long)(row + r) * 768 + col] = (bf16)acc[mi][ni][r];
    }
}

extern "C" void kernel_launch(void* const* d_in, const int* in_sizes, int n_in,
                              void* d_out, int out_size, void* d_ws, size_t ws_size,
                              hipStream_t stream) {
  const float* x      = (const float*)d_in[0];
  const float* w_qkv  = (const float*)d_in[1];
  const float* b_qkv  = (const float*)d_in[2];
  const float* w_proj = (const float*)d_in[3];
  const float* b_proj = (const float*)d_in[4];

  char* ws = (char*)d_ws;
  // Region [0, 100.7MB) is time-shared: Xb (cvt->qkv gemm), then part (attn_qk->softmax),
  // then out2 (attn_v->proj gemm). All uses are stream-ordered.
  bf16*  Xb     = (bf16*)ws;                      // 100,663,296 B
  float* part   = (float*)ws;                     //  37,748,736 B (after Xb dead)
  bf16*  out2   = (bf16*)ws;                      // 100,663,296 B (after part dead)
  bf16*  Wqkvb  = (bf16*)(ws + 100663296);        //   3,538,944 B
  bf16*  Wprojb = (bf16*)(ws + 104202240);        //   1,179,648 B
  bf16*  qkT    = (bf16*)(ws + 105381888);        // 201,326,592 B  [b][1536][4096]
  bf16*  Vb     = (bf16*)(ws + 306708480);        // 100,663,296 B  [b*4096+tok][768]
  bf16*  attnb  = (bf16*)(ws + 407371776);        //   2,359,296 B

  cvt_f32_bf16<<<(12582912 + 255) / 256, 256, 0, stream>>>(x, Xb, 12582912);
  cvt_f32_bf16<<<(442368 + 255) / 256, 256, 0, stream>>>(w_qkv, Wqkvb, 442368);
  cvt_f32_bf16<<<(147456 + 255) / 256, 256, 0, stream>>>(w_proj, Wprojb, 147456);

  // qkv = x @ w_qkv^T + b; q/k -> qkT transposed (q scaled), v -> Vb
  gemm256<0><<<2304, 512, 0, stream>>>(Xb, Wqkvb, b_qkv, qkT, Vb, 2304, 768, 9, 2304);
  // attn partials per (b,h), split-K=8 over tokens
  attn_qk<<<1024, 256, 0, stream>>>(qkT, part);
  softmax_attn<<<128, 256, 0, stream>>>(part, attnb);
  // out2 = (attn @ v^T)^T merged heads -> [65536, 768] bf16
  attn_v<<<4096, 256, 0, stream>>>(Vb, attnb, out2);
  // final: out2 @ w_proj^T + b -> fp32 d_out
  gemm256<1><<<768, 512, 0, stream>>>(out2, Wprojb, b_proj, d_out, nullptr, 768, 768, 3, 768);
}